// Round 3
// baseline (710.984 us; speedup 1.0000x reference)
//
#include <hip/hip_runtime.h>
#include <hip/hip_bf16.h>

// Grid-stride persistent groups of 32 lanes, U triplets per tile.
// Software pipeline: while the current tile's 2*U row-gathers are in flight,
// issue the next tile's index loads, so the wave never sits in a standalone
// index-load latency epoch.
constexpr int U = 4;

__global__ __launch_bounds__(256) void dot_gather_kernel(
    const int* __restrict__ trip,   // (T, 3) int32
    const float* __restrict__ emb,  // (N, 128) fp32
    float* __restrict__ out,        // (T,) fp32
    int T, int ngroups) {
  int gid = blockIdx.x * blockDim.x + threadIdx.x;
  int group = gid >> 5;
  int lane = gid & 31;
  long long ntiles = ((long long)T + U - 1) / U;

  long long tile = group;
  if (tile >= ntiles) return;

  // Prologue: indices for the first tile.
  int iL[U], iR[U];
  {
    long long t0 = tile * U;
    #pragma unroll
    for (int u = 0; u < U; ++u) {
      long long t = (t0 + u < T) ? (t0 + u) : (long long)(T - 1);
      iL[u] = trip[3 * t];
      iR[u] = trip[3 * t + 2];
    }
  }

  while (true) {
    long long t0 = tile * U;
    long long next = tile + ngroups;

    // Issue all row gathers for the current tile (2*U float4 loads in flight).
    float4 a[U], b[U];
    #pragma unroll
    for (int u = 0; u < U; ++u) {
      a[u] = ((const float4*)(emb + (long long)iL[u] * 128))[lane];
      b[u] = ((const float4*)(emb + (long long)iR[u] * 128))[lane];
    }

    // Overlap: fetch the NEXT tile's indices while gathers are in flight.
    int jL[U], jR[U];
    bool have_next = (next < ntiles);
    if (have_next) {
      long long n0 = next * U;
      #pragma unroll
      for (int u = 0; u < U; ++u) {
        long long t = (n0 + u < T) ? (n0 + u) : (long long)(T - 1);
        jL[u] = trip[3 * t];
        jR[u] = trip[3 * t + 2];
      }
    }

    // Dot + 32-lane reduce + store.
    #pragma unroll
    for (int u = 0; u < U; ++u) {
      float s = a[u].x * b[u].x + a[u].y * b[u].y + a[u].z * b[u].z + a[u].w * b[u].w;
      #pragma unroll
      for (int off = 16; off > 0; off >>= 1)
        s += __shfl_down(s, off, 32);
      if (lane == 0 && t0 + u < T)
        __builtin_nontemporal_store(s, &out[t0 + u]);
    }

    if (!have_next) break;
    tile = next;
    #pragma unroll
    for (int u = 0; u < U; ++u) { iL[u] = jL[u]; iR[u] = jR[u]; }
  }
}

extern "C" void kernel_launch(void* const* d_in, const int* in_sizes, int n_in,
                              void* d_out, int out_size, void* d_ws, size_t ws_size,
                              hipStream_t stream) {
  const int* trip = (const int*)d_in[0];     // triplets (T,3) int32
  const float* emb = (const float*)d_in[1];  // node_emb (N,128) fp32
  float* out = (float*)d_out;

  int T = in_sizes[0] / 3;
  int block = 256;
  int grid = 4096;                       // 32768 persistent 32-lane groups
  int ngroups = grid * block / 32;

  dot_gather_kernel<<<grid, block, 0, stream>>>(trip, emb, out, T, ngroups);
}